// Round 12
// baseline (109.756 us; speedup 1.0000x reference)
//
#include <hip/hip_runtime.h>

#define B_   256
#define J_   140
#define VN_  14000
#define NKP  22
#define KP   160        // K padded to multiple of 32
#define MP   4096       // M = B*16
#define NSPLIT 32
#define NT   219        // ceil(VN/64) N-tiles of 64 vertices

#define OFF_J (B_ * VN_ * 3)
#define OFF_K (OFF_J + B_ * J_ * 3)

#define PREPW_BLOCKS ((VN_ * (KP / 8) + 255) / 256)

typedef __attribute__((ext_vector_type(8))) __bf16 bf16x8;
typedef __attribute__((ext_vector_type(4))) float  f32x4;
typedef unsigned int u32;

__device__ __forceinline__ void gload_lds16(const void* g, void* l) {
    __builtin_amdgcn_global_load_lds(
        (const __attribute__((address_space(1))) u32*)g,
        (__attribute__((address_space(3))) u32*)l, 16, 0, 0);
}

// ---------------------------------------------------------------------------
// Kernel 1 (fused): blocks [0,B_) = kinematic chain (barrier-free ancestor
// walk); blocks [B_, B_+PREPW_BLOCKS) = weights -> bf16.  (round-9 exact)
// ---------------------------------------------------------------------------
__global__ __launch_bounds__(256) void prep_kernel(
    const float* __restrict__ rotvec,
    const float* __restrict__ ptrans,
    const float* __restrict__ tpose,
    const void*  __restrict__ parents_raw,
    const float* __restrict__ w,
    __bf16* __restrict__ Abf,
    __bf16* __restrict__ Wbf,
    float*  __restrict__ Jout)
{
    // ---------------- weights cast part ----------------
    if (blockIdx.x >= B_) {
        const int id = (blockIdx.x - B_) * 256 + threadIdx.x;
        if (id < VN_ * (KP / 8)) {
            const int v  = id / (KP / 8);
            const int jc = (id % (KP / 8)) * 8;
            __bf16 tmp[8];
            #pragma unroll
            for (int e = 0; e < 8; ++e) {
                const int j = jc + e;
                tmp[e] = (__bf16)((j < J_) ? w[(size_t)v * J_ + j] : 0.0f);
            }
            *reinterpret_cast<int4*>(Wbf + (size_t)v * KP + jc) =
                *reinterpret_cast<int4*>(tmp);
        }
        return;
    }

    // ---------------- chain part ----------------
    __shared__ float sS[J_][12];
    __shared__ float sA[J_][12];
    __shared__ int   sPar[J_];
    __shared__ int   sNz;

    const int b = blockIdx.x;
    const int t = threadIdx.x;

    if (t == 0) sNz = 0;
    __syncthreads();
    const int* p32 = (const int*)parents_raw;
    if (t < J_ / 2 && p32[2 * t + 1] != 0) atomicOr(&sNz, 1);
    __syncthreads();
    const bool is64 = (sNz == 0);

    if (t < J_) {
        const int j = t;
        int p = is64 ? p32[2 * j] : p32[j];
        if (j == 0 || p < 0 || p >= j) p = 0;
        sPar[j] = p;

        const size_t base = ((size_t)b * J_ + j) * 3;
        const float rx = rotvec[base + 0], ry = rotvec[base + 1], rz = rotvec[base + 2];
        const float th  = sqrtf(rx * rx + ry * ry + rz * rz) + 1e-8f;
        const float inv = 1.0f / th;
        const float ux = rx * inv, uy = ry * inv, uz = rz * inv;
        const float c = cosf(th), s = sinf(th);
        const float omc = 1.0f - c;

        sS[j][0]  = c + omc * ux * ux;
        sS[j][1]  = omc * ux * uy - s * uz;
        sS[j][2]  = omc * ux * uz + s * uy;
        sS[j][4]  = omc * uy * ux + s * uz;
        sS[j][5]  = c + omc * uy * uy;
        sS[j][6]  = omc * uy * uz - s * ux;
        sS[j][8]  = omc * uz * ux - s * uy;
        sS[j][9]  = omc * uz * uy + s * ux;
        sS[j][10] = c + omc * uz * uz;
        sS[j][3]  = ptrans[base + 0];
        sS[j][7]  = ptrans[base + 1];
        sS[j][11] = ptrans[base + 2];
    }
    __syncthreads();

    if (t < J_) {
        const int j = t;
        float g[12];
        #pragma unroll
        for (int q = 0; q < 12; ++q) g[q] = sS[j][q];

        int cur = j;
        for (int it = 0; it < J_ && cur != 0; ++it) {
            const int p = sPar[cur];
            float ng[12];
            #pragma unroll
            for (int m = 0; m < 3; ++m) {
                const float s0 = sS[p][m*4+0], s1 = sS[p][m*4+1];
                const float s2 = sS[p][m*4+2], s3 = sS[p][m*4+3];
                #pragma unroll
                for (int cc = 0; cc < 4; ++cc)
                    ng[m*4+cc] = s0 * g[0*4+cc] + s1 * g[1*4+cc] + s2 * g[2*4+cc]
                               + ((cc == 3) ? s3 : 0.0f);
            }
            #pragma unroll
            for (int q = 0; q < 12; ++q) g[q] = ng[q];
            cur = p;
        }

        const float tx = tpose[j*3+0], ty = tpose[j*3+1], tz = tpose[j*3+2];
        #pragma unroll
        for (int m = 0; m < 3; ++m) {
            const float r0 = g[m*4+0], r1 = g[m*4+1], r2 = g[m*4+2];
            const float gt = g[m*4+3];
            sA[j][m*4+0] = r0;
            sA[j][m*4+1] = r1;
            sA[j][m*4+2] = r2;
            sA[j][m*4+3] = gt - (r0 * tx + r1 * ty + r2 * tz);
            Jout[((size_t)b * J_ + j) * 3 + m] = gt;
        }
    }
    __syncthreads();

    for (int idx = t; idx < 16 * KP; idx += 256) {
        const int comp = idx / KP, j = idx % KP;
        const float val = (comp < 12 && j < J_) ? sA[j][comp] : 0.0f;
        Abf[((size_t)b * 16 + comp) * KP + j] = (__bf16)val;
    }
}

// ---------------------------------------------------------------------------
// Kernel 2: GEMM + fused LBS epilogue. SINGLE-buffer, occupancy-first:
// LDS = 20KB sB + 20KB sE = 40KB -> 4 blocks/CU (16 waves/CU), 2x round 9.
// Per iter: stage -> vmcnt(0)+barrier -> 80 MFMA -> epilogue -> barrier.
// Block = 4 waves, wave owns 4 batches; fragment-order LDS (conflict-free).
// ---------------------------------------------------------------------------
__global__ __launch_bounds__(256, 4) void gemm_kernel(
    const __bf16* __restrict__ Abf,   // (MP, KP)
    const __bf16* __restrict__ Wbf,   // (VN, KP)
    const float*  __restrict__ vt,    // (VN, 3)
    float* __restrict__ out)          // (B, VN, 3)
{
    __shared__ __bf16 sB[4 * 5 * 64 * 8];       // 20 KB
    __shared__ float  sE[4][4][64 * 5];         // 20 KB epilogue scratch

    const int lane = threadIdx.x & 63;
    const int w    = threadIdx.x >> 6;
    const int r    = lane & 15;
    const int q    = lane >> 4;
    const int q16  = q * 16;                    // byte offset of k-quad
    const int batch0 = blockIdx.y * 16;
    const int row0   = blockIdx.y * 256;

    // ---- A fragments straight from global (L2-hot): 4 x 5 x 16B per lane
    bf16x8 afrag[4][5];
    #pragma unroll
    for (int mi = 0; mi < 4; ++mi) {
        const char* g = (const char*)(Abf + (size_t)(row0 + (w * 4 + mi) * 16 + r) * KP) + q16;
        #pragma unroll
        for (int s = 0; s < 5; ++s)
            afrag[mi][s] = *reinterpret_cast<const bf16x8*>(g + s * 64);
    }

    for (int t = blockIdx.x; t < NT; t += NSPLIT) {
        // ---- stage B tile into sB (wave w stages frag f = w)
        {
            int v = t * 64 + w * 16 + r;
            if (v >= VN_) v = VN_ - 1;
            const char* g = (const char*)(Wbf + (size_t)v * KP) + q16;
            char* lb = (char*)&sB[0] + w * 5 * 1024;
            #pragma unroll
            for (int s = 0; s < 5; ++s)
                gload_lds16(g + s * 64, lb + s * 1024);
        }
        asm volatile("s_waitcnt vmcnt(0)" ::: "memory");
        __builtin_amdgcn_s_barrier();
        asm volatile("" ::: "memory");

        // ---- compute: 80 MFMA per wave from sB
        f32x4 acc[4][4];
        #pragma unroll
        for (int mi = 0; mi < 4; ++mi)
            #pragma unroll
            for (int f = 0; f < 4; ++f)
                acc[mi][f] = (f32x4){0.f, 0.f, 0.f, 0.f};

        #pragma unroll
        for (int f = 0; f < 4; ++f) {
            #pragma unroll
            for (int s = 0; s < 5; ++s) {
                const bf16x8 bf = *reinterpret_cast<const bf16x8*>(
                    &sB[((f * 5 + s) * 64 + lane) * 8]);
                #pragma unroll
                for (int mi = 0; mi < 4; ++mi)
                    acc[mi][f] = __builtin_amdgcn_mfma_f32_16x16x32_bf16(
                        afrag[mi][s], bf, acc[mi][f], 0, 0, 0);
            }
        }

        // ---- fused epilogue: LDS transpose (same-wave) + dense float3 stores
        const int n0 = t * 64;
        #pragma unroll
        for (int f = 0; f < 4; ++f) {
            const int v  = n0 + f * 16 + r;
            const int vc = (v < VN_) ? v : VN_ - 1;
            const float3 p = *reinterpret_cast<const float3*>(vt + 3 * (size_t)vc);
            if (q < 3) {
                #pragma unroll
                for (int mi = 0; mi < 4; ++mi) {
                    const f32x4 c = acc[mi][f];
                    sE[w][mi][(f * 16 + r) * 5 + q] =
                        c[0] * p.x + c[1] * p.y + c[2] * p.z + c[3];
                }
            }
        }
        const int vst = n0 + lane;
        if (vst < VN_) {
            #pragma unroll
            for (int mi = 0; mi < 4; ++mi) {
                const float x = sE[w][mi][lane * 5 + 0];
                const float y = sE[w][mi][lane * 5 + 1];
                const float z = sE[w][mi][lane * 5 + 2];
                float* o = out + ((size_t)(batch0 + w * 4 + mi) * VN_ + vst) * 3;
                o[0] = x; o[1] = y; o[2] = z;
            }
        }

        __builtin_amdgcn_s_barrier();   // sB consumed by all waves; safe to restage
    }
}

// ---------------------------------------------------------------------------
// Kernel 3: keypoints.
// ---------------------------------------------------------------------------
__global__ __launch_bounds__(256) void kp_kernel(
    const int* __restrict__ kpv, const int* __restrict__ kpj,
    const int* __restrict__ kpb, float* __restrict__ out)
{
    const int i = blockIdx.x * 256 + threadIdx.x;
    if (i >= B_ * NKP) return;
    const int b  = i / NKP;
    const int kk = i - b * NKP;

    float vx, vy, vz;
    if (kpb[kk] != 0) {
        int j0 = kpj[kk * 2 + 0], j1 = kpj[kk * 2 + 1];
        if (j0 < 0 || j0 >= J_) j0 = 0;
        if (j1 < 0 || j1 >= J_) j1 = 0;
        const float* p0 = out + OFF_J + ((size_t)b * J_ + j0) * 3;
        const float* p1 = out + OFF_J + ((size_t)b * J_ + j1) * 3;
        vx = 0.5f * (p0[0] + p1[0]);
        vy = 0.5f * (p0[1] + p1[1]);
        vz = 0.5f * (p0[2] + p1[2]);
    } else {
        vx = vy = vz = 0.0f;
        #pragma unroll
        for (int qq = 0; qq < 4; ++qq) {
            int vid = kpv[kk * 4 + qq];
            if (vid < 0 || vid >= VN_) vid = 0;
            const float* p = out + ((size_t)b * VN_ + vid) * 3;
            vx += p[0]; vy += p[1]; vz += p[2];
        }
        vx *= 0.25f; vy *= 0.25f; vz *= 0.25f;
    }
    float* o = out + OFF_K + ((size_t)b * NKP + kk) * 3;
    o[0] = vx; o[1] = vy; o[2] = vz;
}

// ---------------------------------------------------------------------------
extern "C" void kernel_launch(void* const* d_in, const int* in_sizes, int n_in,
                              void* d_out, int out_size, void* d_ws, size_t ws_size,
                              hipStream_t stream) {
    const float* rotvec  = (const float*)d_in[0];
    const float* ptrans  = (const float*)d_in[1];
    const float* vt      = (const float*)d_in[2];
    const float* w       = (const float*)d_in[3];
    const float* tpose   = (const float*)d_in[4];
    const void*  parents = (const void*)d_in[5];
    const int*   kpv     = (const int*)d_in[6];
    const int*   kpj     = (const int*)d_in[7];
    const int*   kpb     = (const int*)d_in[8];

    float*  out = (float*)d_out;
    __bf16* Abf = (__bf16*)d_ws;                               // 1.31 MB
    __bf16* Wbf = (__bf16*)((char*)d_ws + (size_t)MP * KP * 2); // 4.48 MB

    prep_kernel<<<B_ + PREPW_BLOCKS, 256, 0, stream>>>(
        rotvec, ptrans, tpose, parents, w, Abf, Wbf, out + OFF_J);

    dim3 grid(NSPLIT, MP / 256);    // (32, 16) = 512 blocks
    gemm_kernel<<<grid, 256, 0, stream>>>(Abf, Wbf, vt, out);

    kp_kernel<<<(B_ * NKP + 255) / 256, 256, 0, stream>>>(kpv, kpj, kpb, out);
}

// Round 13
// 43.455 us; speedup vs baseline: 2.5258x; 2.5258x over previous
//
#include <hip/hip_runtime.h>

#define B_   256
#define J_   140
#define VN_  14000
#define NKP  22
#define KP   160        // K padded to multiple of 32
#define MP   4096       // M = B*16
#define NSPLIT 48
#define NT   219        // ceil(VN/64) N-tiles of 64 vertices

#define OFF_J (B_ * VN_ * 3)
#define OFF_K (OFF_J + B_ * J_ * 3)

#define PREPW_BLOCKS ((VN_ * (KP / 8) + 255) / 256)

typedef __attribute__((ext_vector_type(8))) __bf16 bf16x8;
typedef __attribute__((ext_vector_type(4))) float  f32x4;
typedef unsigned int u32;

__device__ __forceinline__ void gload_lds16(const void* g, void* l) {
    __builtin_amdgcn_global_load_lds(
        (const __attribute__((address_space(1))) u32*)g,
        (__attribute__((address_space(3))) u32*)l, 16, 0, 0);
}

// ---------------------------------------------------------------------------
// Kernel 1 (fused): blocks [0,B_) = kinematic chain (barrier-free ancestor
// walk); blocks [B_, B_+PREPW_BLOCKS) = weights -> bf16.  (round-9 exact)
// ---------------------------------------------------------------------------
__global__ __launch_bounds__(256) void prep_kernel(
    const float* __restrict__ rotvec,
    const float* __restrict__ ptrans,
    const float* __restrict__ tpose,
    const void*  __restrict__ parents_raw,
    const float* __restrict__ w,
    __bf16* __restrict__ Abf,
    __bf16* __restrict__ Wbf,
    float*  __restrict__ Jout)
{
    // ---------------- weights cast part ----------------
    if (blockIdx.x >= B_) {
        const int id = (blockIdx.x - B_) * 256 + threadIdx.x;
        if (id < VN_ * (KP / 8)) {
            const int v  = id / (KP / 8);
            const int jc = (id % (KP / 8)) * 8;
            __bf16 tmp[8];
            #pragma unroll
            for (int e = 0; e < 8; ++e) {
                const int j = jc + e;
                tmp[e] = (__bf16)((j < J_) ? w[(size_t)v * J_ + j] : 0.0f);
            }
            *reinterpret_cast<int4*>(Wbf + (size_t)v * KP + jc) =
                *reinterpret_cast<int4*>(tmp);
        }
        return;
    }

    // ---------------- chain part ----------------
    __shared__ float sS[J_][12];
    __shared__ float sA[J_][12];
    __shared__ int   sPar[J_];
    __shared__ int   sNz;

    const int b = blockIdx.x;
    const int t = threadIdx.x;

    if (t == 0) sNz = 0;
    __syncthreads();
    const int* p32 = (const int*)parents_raw;
    if (t < J_ / 2 && p32[2 * t + 1] != 0) atomicOr(&sNz, 1);
    __syncthreads();
    const bool is64 = (sNz == 0);

    if (t < J_) {
        const int j = t;
        int p = is64 ? p32[2 * j] : p32[j];
        if (j == 0 || p < 0 || p >= j) p = 0;
        sPar[j] = p;

        const size_t base = ((size_t)b * J_ + j) * 3;
        const float rx = rotvec[base + 0], ry = rotvec[base + 1], rz = rotvec[base + 2];
        const float th  = sqrtf(rx * rx + ry * ry + rz * rz) + 1e-8f;
        const float inv = 1.0f / th;
        const float ux = rx * inv, uy = ry * inv, uz = rz * inv;
        const float c = cosf(th), s = sinf(th);
        const float omc = 1.0f - c;

        sS[j][0]  = c + omc * ux * ux;
        sS[j][1]  = omc * ux * uy - s * uz;
        sS[j][2]  = omc * ux * uz + s * uy;
        sS[j][4]  = omc * uy * ux + s * uz;
        sS[j][5]  = c + omc * uy * uy;
        sS[j][6]  = omc * uy * uz - s * ux;
        sS[j][8]  = omc * uz * ux - s * uy;
        sS[j][9]  = omc * uz * uy + s * ux;
        sS[j][10] = c + omc * uz * uz;
        sS[j][3]  = ptrans[base + 0];
        sS[j][7]  = ptrans[base + 1];
        sS[j][11] = ptrans[base + 2];
    }
    __syncthreads();

    if (t < J_) {
        const int j = t;
        float g[12];
        #pragma unroll
        for (int q = 0; q < 12; ++q) g[q] = sS[j][q];

        int cur = j;
        for (int it = 0; it < J_ && cur != 0; ++it) {
            const int p = sPar[cur];
            float ng[12];
            #pragma unroll
            for (int m = 0; m < 3; ++m) {
                const float s0 = sS[p][m*4+0], s1 = sS[p][m*4+1];
                const float s2 = sS[p][m*4+2], s3 = sS[p][m*4+3];
                #pragma unroll
                for (int cc = 0; cc < 4; ++cc)
                    ng[m*4+cc] = s0 * g[0*4+cc] + s1 * g[1*4+cc] + s2 * g[2*4+cc]
                               + ((cc == 3) ? s3 : 0.0f);
            }
            #pragma unroll
            for (int q = 0; q < 12; ++q) g[q] = ng[q];
            cur = p;
        }

        const float tx = tpose[j*3+0], ty = tpose[j*3+1], tz = tpose[j*3+2];
        #pragma unroll
        for (int m = 0; m < 3; ++m) {
            const float r0 = g[m*4+0], r1 = g[m*4+1], r2 = g[m*4+2];
            const float gt = g[m*4+3];
            sA[j][m*4+0] = r0;
            sA[j][m*4+1] = r1;
            sA[j][m*4+2] = r2;
            sA[j][m*4+3] = gt - (r0 * tx + r1 * ty + r2 * tz);
            Jout[((size_t)b * J_ + j) * 3 + m] = gt;
        }
    }
    __syncthreads();

    for (int idx = t; idx < 16 * KP; idx += 256) {
        const int comp = idx / KP, j = idx % KP;
        const float val = (comp < 12 && j < J_) ? sA[j][comp] : 0.0f;
        Abf[((size_t)b * 16 + comp) * KP + j] = (__bf16)val;
    }
}

// ---------------------------------------------------------------------------
// Kernel 2: GEMM + fused LBS epilogue. Round-9 schedule (2-buffer prefetch,
// epilogue before the drain) + occupancy package: sE halved to 10KB via
// two 2-mi epilogue groups -> LDS 50KB -> 3 blocks/CU; grid 768 (NSPLIT 48).
// ---------------------------------------------------------------------------
__global__ __launch_bounds__(256, 3) void gemm_kernel(
    const __bf16* __restrict__ Abf,   // (MP, KP)
    const __bf16* __restrict__ Wbf,   // (VN, KP)
    const float*  __restrict__ vt,    // (VN, 3)
    float* __restrict__ out)          // (B, VN, 3)
{
    __shared__ __bf16 sB[2][4 * 5 * 64 * 8];    // 2 x 20 KB
    __shared__ float  sE[4][2][64 * 5];         // 10 KB epilogue scratch

    const int lane = threadIdx.x & 63;
    const int w    = threadIdx.x >> 6;
    const int r    = lane & 15;
    const int q    = lane >> 4;
    const int q16  = q * 16;                    // byte offset of k-quad
    const int batch0 = blockIdx.y * 16;
    const int row0   = blockIdx.y * 256;

    // ---- A fragments straight from global (L2-hot): 4 x 5 x 16B per lane
    bf16x8 afrag[4][5];
    #pragma unroll
    for (int mi = 0; mi < 4; ++mi) {
        const char* g = (const char*)(Abf + (size_t)(row0 + (w * 4 + mi) * 16 + r) * KP) + q16;
        #pragma unroll
        for (int s = 0; s < 5; ++s)
            afrag[mi][s] = *reinterpret_cast<const bf16x8*>(g + s * 64);
    }

    // ---- stage B tile 0: wave w stages frag f = w
    {
        int v = blockIdx.x * 64 + w * 16 + r;
        if (v >= VN_) v = VN_ - 1;
        const char* g = (const char*)(Wbf + (size_t)v * KP) + q16;
        char* lb = (char*)&sB[0][0] + w * 5 * 1024;
        #pragma unroll
        for (int s = 0; s < 5; ++s)
            gload_lds16(g + s * 64, lb + s * 1024);
    }
    asm volatile("s_waitcnt vmcnt(0)" ::: "memory");
    __syncthreads();

    int cur = 0;
    for (int t = blockIdx.x; t < NT; t += NSPLIT) {
        // ---- prefetch next B tile into other buffer (async)
        const int tn = t + NSPLIT;
        if (tn < NT) {
            int v = tn * 64 + w * 16 + r;
            if (v >= VN_) v = VN_ - 1;
            const char* g = (const char*)(Wbf + (size_t)v * KP) + q16;
            char* lb = (char*)&sB[cur ^ 1][0] + w * 5 * 1024;
            #pragma unroll
            for (int s = 0; s < 5; ++s)
                gload_lds16(g + s * 64, lb + s * 1024);
        }

        // ---- compute: 80 MFMA per wave from sB[cur]
        f32x4 acc[4][4];
        #pragma unroll
        for (int mi = 0; mi < 4; ++mi)
            #pragma unroll
            for (int f = 0; f < 4; ++f)
                acc[mi][f] = (f32x4){0.f, 0.f, 0.f, 0.f};

        #pragma unroll
        for (int f = 0; f < 4; ++f) {
            #pragma unroll
            for (int s = 0; s < 5; ++s) {
                const bf16x8 bf = *reinterpret_cast<const bf16x8*>(
                    &sB[cur][((f * 5 + s) * 64 + lane) * 8]);
                #pragma unroll
                for (int mi = 0; mi < 4; ++mi)
                    acc[mi][f] = __builtin_amdgcn_mfma_f32_16x16x32_bf16(
                        afrag[mi][s], bf, acc[mi][f], 0, 0, 0);
            }
        }

        // ---- epilogue BEFORE the drain (doesn't touch sB): two 2-mi groups
        const int n0  = t * 64;
        const int vst = n0 + lane;
        float3 p[4];
        #pragma unroll
        for (int f = 0; f < 4; ++f) {
            const int v  = n0 + f * 16 + r;
            const int vc = (v < VN_) ? v : VN_ - 1;
            p[f] = *reinterpret_cast<const float3*>(vt + 3 * (size_t)vc);
        }
        #pragma unroll
        for (int g = 0; g < 2; ++g) {
            if (q < 3) {
                #pragma unroll
                for (int mig = 0; mig < 2; ++mig) {
                    #pragma unroll
                    for (int f = 0; f < 4; ++f) {
                        const f32x4 c = acc[g * 2 + mig][f];
                        sE[w][mig][(f * 16 + r) * 5 + q] =
                            c[0] * p[f].x + c[1] * p[f].y + c[2] * p[f].z + c[3];
                    }
                }
            }
            if (vst < VN_) {
                #pragma unroll
                for (int mig = 0; mig < 2; ++mig) {
                    const float x = sE[w][mig][lane * 5 + 0];
                    const float y = sE[w][mig][lane * 5 + 1];
                    const float z = sE[w][mig][lane * 5 + 2];
                    float* o = out + ((size_t)(batch0 + w * 4 + g * 2 + mig) * VN_ + vst) * 3;
                    o[0] = x; o[1] = y; o[2] = z;
                }
            }
        }

        asm volatile("s_waitcnt vmcnt(0)" ::: "memory");
        __syncthreads();
        cur ^= 1;
    }
}

// ---------------------------------------------------------------------------
// Kernel 3: keypoints.
// ---------------------------------------------------------------------------
__global__ __launch_bounds__(256) void kp_kernel(
    const int* __restrict__ kpv, const int* __restrict__ kpj,
    const int* __restrict__ kpb, float* __restrict__ out)
{
    const int i = blockIdx.x * 256 + threadIdx.x;
    if (i >= B_ * NKP) return;
    const int b  = i / NKP;
    const int kk = i - b * NKP;

    float vx, vy, vz;
    if (kpb[kk] != 0) {
        int j0 = kpj[kk * 2 + 0], j1 = kpj[kk * 2 + 1];
        if (j0 < 0 || j0 >= J_) j0 = 0;
        if (j1 < 0 || j1 >= J_) j1 = 0;
        const float* p0 = out + OFF_J + ((size_t)b * J_ + j0) * 3;
        const float* p1 = out + OFF_J + ((size_t)b * J_ + j1) * 3;
        vx = 0.5f * (p0[0] + p1[0]);
        vy = 0.5f * (p0[1] + p1[1]);
        vz = 0.5f * (p0[2] + p1[2]);
    } else {
        vx = vy = vz = 0.0f;
        #pragma unroll
        for (int qq = 0; qq < 4; ++qq) {
            int vid = kpv[kk * 4 + qq];
            if (vid < 0 || vid >= VN_) vid = 0;
            const float* p = out + ((size_t)b * VN_ + vid) * 3;
            vx += p[0]; vy += p[1]; vz += p[2];
        }
        vx *= 0.25f; vy *= 0.25f; vz *= 0.25f;
    }
    float* o = out + OFF_K + ((size_t)b * NKP + kk) * 3;
    o[0] = vx; o[1] = vy; o[2] = vz;
}

// ---------------------------------------------------------------------------
extern "C" void kernel_launch(void* const* d_in, const int* in_sizes, int n_in,
                              void* d_out, int out_size, void* d_ws, size_t ws_size,
                              hipStream_t stream) {
    const float* rotvec  = (const float*)d_in[0];
    const float* ptrans  = (const float*)d_in[1];
    const float* vt      = (const float*)d_in[2];
    const float* w       = (const float*)d_in[3];
    const float* tpose   = (const float*)d_in[4];
    const void*  parents = (const void*)d_in[5];
    const int*   kpv     = (const int*)d_in[6];
    const int*   kpj     = (const int*)d_in[7];
    const int*   kpb     = (const int*)d_in[8];

    float*  out = (float*)d_out;
    __bf16* Abf = (__bf16*)d_ws;                               // 1.31 MB
    __bf16* Wbf = (__bf16*)((char*)d_ws + (size_t)MP * KP * 2); // 4.48 MB

    prep_kernel<<<B_ + PREPW_BLOCKS, 256, 0, stream>>>(
        rotvec, ptrans, tpose, parents, w, Abf, Wbf, out + OFF_J);

    dim3 grid(NSPLIT, MP / 256);    // (48, 16) = 768 blocks
    gemm_kernel<<<grid, 256, 0, stream>>>(Abf, Wbf, vt, out);

    kp_kernel<<<(B_ * NKP + 255) / 256, 256, 0, stream>>>(kpv, kpj, kpb, out);
}

// Round 14
// 36.408 us; speedup vs baseline: 3.0146x; 1.1935x over previous
//
#include <hip/hip_runtime.h>

#define B_   256
#define J_   140
#define VN_  14000
#define NKP  22
#define KP   160        // K padded to multiple of 32
#define MP12 3072       // M = B*12 (packed: only the 12 real components)
#define NSPLIT 32
#define NT   219        // ceil(VN/64) N-tiles of 64 vertices

#define OFF_J (B_ * VN_ * 3)
#define OFF_K (OFF_J + B_ * J_ * 3)

#define PREPW_BLOCKS ((VN_ * (KP / 8) + 255) / 256)

typedef __attribute__((ext_vector_type(8))) __bf16 bf16x8;
typedef __attribute__((ext_vector_type(4))) float  f32x4;
typedef unsigned int u32;

__device__ __forceinline__ void gload_lds16(const void* g, void* l) {
    __builtin_amdgcn_global_load_lds(
        (const __attribute__((address_space(1))) u32*)g,
        (__attribute__((address_space(3))) u32*)l, 16, 0, 0);
}

// ---------------------------------------------------------------------------
// Kernel 1 (fused): blocks [0,B_) = kinematic chain (barrier-free ancestor
// walk); blocks [B_, B_+PREPW_BLOCKS) = weights -> bf16.
// A is emitted PACKED: Abf[(b*12+comp)*KP + j], comp 0..11 only.
// ---------------------------------------------------------------------------
__global__ __launch_bounds__(256) void prep_kernel(
    const float* __restrict__ rotvec,
    const float* __restrict__ ptrans,
    const float* __restrict__ tpose,
    const void*  __restrict__ parents_raw,
    const float* __restrict__ w,
    __bf16* __restrict__ Abf,
    __bf16* __restrict__ Wbf,
    float*  __restrict__ Jout)
{
    // ---------------- weights cast part ----------------
    if (blockIdx.x >= B_) {
        const int id = (blockIdx.x - B_) * 256 + threadIdx.x;
        if (id < VN_ * (KP / 8)) {
            const int v  = id / (KP / 8);
            const int jc = (id % (KP / 8)) * 8;
            __bf16 tmp[8];
            #pragma unroll
            for (int e = 0; e < 8; ++e) {
                const int j = jc + e;
                tmp[e] = (__bf16)((j < J_) ? w[(size_t)v * J_ + j] : 0.0f);
            }
            *reinterpret_cast<int4*>(Wbf + (size_t)v * KP + jc) =
                *reinterpret_cast<int4*>(tmp);
        }
        return;
    }

    // ---------------- chain part ----------------
    __shared__ float sS[J_][12];
    __shared__ float sA[J_][12];
    __shared__ int   sPar[J_];
    __shared__ int   sNz;

    const int b = blockIdx.x;
    const int t = threadIdx.x;

    if (t == 0) sNz = 0;
    __syncthreads();
    const int* p32 = (const int*)parents_raw;
    if (t < J_ / 2 && p32[2 * t + 1] != 0) atomicOr(&sNz, 1);
    __syncthreads();
    const bool is64 = (sNz == 0);

    if (t < J_) {
        const int j = t;
        int p = is64 ? p32[2 * j] : p32[j];
        if (j == 0 || p < 0 || p >= j) p = 0;
        sPar[j] = p;

        const size_t base = ((size_t)b * J_ + j) * 3;
        const float rx = rotvec[base + 0], ry = rotvec[base + 1], rz = rotvec[base + 2];
        const float th  = sqrtf(rx * rx + ry * ry + rz * rz) + 1e-8f;
        const float inv = 1.0f / th;
        const float ux = rx * inv, uy = ry * inv, uz = rz * inv;
        const float c = cosf(th), s = sinf(th);
        const float omc = 1.0f - c;

        sS[j][0]  = c + omc * ux * ux;
        sS[j][1]  = omc * ux * uy - s * uz;
        sS[j][2]  = omc * ux * uz + s * uy;
        sS[j][4]  = omc * uy * ux + s * uz;
        sS[j][5]  = c + omc * uy * uy;
        sS[j][6]  = omc * uy * uz - s * ux;
        sS[j][8]  = omc * uz * ux - s * uy;
        sS[j][9]  = omc * uz * uy + s * ux;
        sS[j][10] = c + omc * uz * uz;
        sS[j][3]  = ptrans[base + 0];
        sS[j][7]  = ptrans[base + 1];
        sS[j][11] = ptrans[base + 2];
    }
    __syncthreads();

    if (t < J_) {
        const int j = t;
        float g[12];
        #pragma unroll
        for (int q = 0; q < 12; ++q) g[q] = sS[j][q];

        int cur = j;
        for (int it = 0; it < J_ && cur != 0; ++it) {
            const int p = sPar[cur];
            float ng[12];
            #pragma unroll
            for (int m = 0; m < 3; ++m) {
                const float s0 = sS[p][m*4+0], s1 = sS[p][m*4+1];
                const float s2 = sS[p][m*4+2], s3 = sS[p][m*4+3];
                #pragma unroll
                for (int cc = 0; cc < 4; ++cc)
                    ng[m*4+cc] = s0 * g[0*4+cc] + s1 * g[1*4+cc] + s2 * g[2*4+cc]
                               + ((cc == 3) ? s3 : 0.0f);
            }
            #pragma unroll
            for (int q = 0; q < 12; ++q) g[q] = ng[q];
            cur = p;
        }

        const float tx = tpose[j*3+0], ty = tpose[j*3+1], tz = tpose[j*3+2];
        #pragma unroll
        for (int m = 0; m < 3; ++m) {
            const float r0 = g[m*4+0], r1 = g[m*4+1], r2 = g[m*4+2];
            const float gt = g[m*4+3];
            sA[j][m*4+0] = r0;
            sA[j][m*4+1] = r1;
            sA[j][m*4+2] = r2;
            sA[j][m*4+3] = gt - (r0 * tx + r1 * ty + r2 * tz);
            Jout[((size_t)b * J_ + j) * 3 + m] = gt;
        }
    }
    __syncthreads();

    // packed bf16 A write: comp-major [12][KP]
    for (int idx = t; idx < 12 * KP; idx += 256) {
        const int comp = idx / KP, j = idx % KP;
        const float val = (j < J_) ? sA[j][comp] : 0.0f;
        Abf[((size_t)b * 12 + comp) * KP + j] = (__bf16)val;
    }
}

// ---------------------------------------------------------------------------
// Kernel 2: GEMM + fused LBS epilogue. Round-9 schedule (best measured),
// with 12-comp packed A: wave owns 4 batches = 48 M-rows = 3 MFMA tiles
// (was 4). 60 MFMA / 20 ds_read_b128 per iter; ALL 64 lanes productive in
// the epilogue. Quad mq = mi*4+q -> local batch mq/3, out component mq%3.
// ---------------------------------------------------------------------------
__global__ __launch_bounds__(256, 2) void gemm_kernel(
    const __bf16* __restrict__ Abf,   // (MP12, KP)
    const __bf16* __restrict__ Wbf,   // (VN, KP)
    const float*  __restrict__ vt,    // (VN, 3)
    float* __restrict__ out)          // (B, VN, 3)
{
    __shared__ __bf16 sB[2][4 * 5 * 64 * 8];    // 2 x 20 KB
    __shared__ float  sE[4][4][64 * 5];         // 20 KB: [wave][lb][v*5+cg]

    const int lane = threadIdx.x & 63;
    const int w    = threadIdx.x >> 6;
    const int r    = lane & 15;
    const int q    = lane >> 4;
    const int q16  = q * 16;                    // byte offset of k-quad
    const int batch0 = blockIdx.y * 16;
    const int rowW   = (batch0 + w * 4) * 12;   // wave's first packed A-row

    // ---- A fragments straight from global (L2-hot): 3 x 5 x 16B per lane
    bf16x8 afrag[3][5];
    #pragma unroll
    for (int mi = 0; mi < 3; ++mi) {
        const char* g = (const char*)(Abf + (size_t)(rowW + mi * 16 + r) * KP) + q16;
        #pragma unroll
        for (int s = 0; s < 5; ++s)
            afrag[mi][s] = *reinterpret_cast<const bf16x8*>(g + s * 64);
    }

    // ---- stage B tile 0: wave w stages frag f = w
    {
        int v = blockIdx.x * 64 + w * 16 + r;
        if (v >= VN_) v = VN_ - 1;
        const char* g = (const char*)(Wbf + (size_t)v * KP) + q16;
        char* lb = (char*)&sB[0][0] + w * 5 * 1024;
        #pragma unroll
        for (int s = 0; s < 5; ++s)
            gload_lds16(g + s * 64, lb + s * 1024);
    }
    asm volatile("s_waitcnt vmcnt(0)" ::: "memory");
    __syncthreads();

    int cur = 0;
    for (int t = blockIdx.x; t < NT; t += NSPLIT) {
        // ---- prefetch next B tile into other buffer (async)
        const int tn = t + NSPLIT;
        if (tn < NT) {
            int v = tn * 64 + w * 16 + r;
            if (v >= VN_) v = VN_ - 1;
            const char* g = (const char*)(Wbf + (size_t)v * KP) + q16;
            char* lb = (char*)&sB[cur ^ 1][0] + w * 5 * 1024;
            #pragma unroll
            for (int s = 0; s < 5; ++s)
                gload_lds16(g + s * 64, lb + s * 1024);
        }

        // ---- compute: 60 MFMA per wave from sB[cur]
        f32x4 acc[3][4];
        #pragma unroll
        for (int mi = 0; mi < 3; ++mi)
            #pragma unroll
            for (int f = 0; f < 4; ++f)
                acc[mi][f] = (f32x4){0.f, 0.f, 0.f, 0.f};

        #pragma unroll
        for (int f = 0; f < 4; ++f) {
            #pragma unroll
            for (int s = 0; s < 5; ++s) {
                const bf16x8 bf = *reinterpret_cast<const bf16x8*>(
                    &sB[cur][((f * 5 + s) * 64 + lane) * 8]);
                #pragma unroll
                for (int mi = 0; mi < 3; ++mi)
                    acc[mi][f] = __builtin_amdgcn_mfma_f32_16x16x32_bf16(
                        afrag[mi][s], bf, acc[mi][f], 0, 0, 0);
            }
        }

        // ---- epilogue BEFORE the drain (doesn't touch sB).
        // quad mq = mi*4+q -> local batch lb = mq/3, component cg = mq%3.
        const int n0 = t * 64;
        float3 p[4];
        #pragma unroll
        for (int f = 0; f < 4; ++f) {
            const int v  = n0 + f * 16 + r;
            const int vc = (v < VN_) ? v : VN_ - 1;
            p[f] = *reinterpret_cast<const float3*>(vt + 3 * (size_t)vc);
        }
        #pragma unroll
        for (int mi = 0; mi < 3; ++mi) {
            const int mq = mi * 4 + q;
            const int lb = mq / 3;
            const int cg = mq - lb * 3;
            #pragma unroll
            for (int f = 0; f < 4; ++f) {
                const f32x4 c = acc[mi][f];
                sE[w][lb][(f * 16 + r) * 5 + cg] =
                    c[0] * p[f].x + c[1] * p[f].y + c[2] * p[f].z + c[3];
            }
        }
        const int vst = n0 + lane;
        if (vst < VN_) {
            #pragma unroll
            for (int lb = 0; lb < 4; ++lb) {
                const float x = sE[w][lb][lane * 5 + 0];
                const float y = sE[w][lb][lane * 5 + 1];
                const float z = sE[w][lb][lane * 5 + 2];
                float* o = out + ((size_t)(batch0 + w * 4 + lb) * VN_ + vst) * 3;
                o[0] = x; o[1] = y; o[2] = z;
            }
        }

        asm volatile("s_waitcnt vmcnt(0)" ::: "memory");
        __syncthreads();
        cur ^= 1;
    }
}

// ---------------------------------------------------------------------------
// Kernel 3: keypoints.
// ---------------------------------------------------------------------------
__global__ __launch_bounds__(256) void kp_kernel(
    const int* __restrict__ kpv, const int* __restrict__ kpj,
    const int* __restrict__ kpb, float* __restrict__ out)
{
    const int i = blockIdx.x * 256 + threadIdx.x;
    if (i >= B_ * NKP) return;
    const int b  = i / NKP;
    const int kk = i - b * NKP;

    float vx, vy, vz;
    if (kpb[kk] != 0) {
        int j0 = kpj[kk * 2 + 0], j1 = kpj[kk * 2 + 1];
        if (j0 < 0 || j0 >= J_) j0 = 0;
        if (j1 < 0 || j1 >= J_) j1 = 0;
        const float* p0 = out + OFF_J + ((size_t)b * J_ + j0) * 3;
        const float* p1 = out + OFF_J + ((size_t)b * J_ + j1) * 3;
        vx = 0.5f * (p0[0] + p1[0]);
        vy = 0.5f * (p0[1] + p1[1]);
        vz = 0.5f * (p0[2] + p1[2]);
    } else {
        vx = vy = vz = 0.0f;
        #pragma unroll
        for (int qq = 0; qq < 4; ++qq) {
            int vid = kpv[kk * 4 + qq];
            if (vid < 0 || vid >= VN_) vid = 0;
            const float* p = out + ((size_t)b * VN_ + vid) * 3;
            vx += p[0]; vy += p[1]; vz += p[2];
        }
        vx *= 0.25f; vy *= 0.25f; vz *= 0.25f;
    }
    float* o = out + OFF_K + ((size_t)b * NKP + kk) * 3;
    o[0] = vx; o[1] = vy; o[2] = vz;
}

// ---------------------------------------------------------------------------
extern "C" void kernel_launch(void* const* d_in, const int* in_sizes, int n_in,
                              void* d_out, int out_size, void* d_ws, size_t ws_size,
                              hipStream_t stream) {
    const float* rotvec  = (const float*)d_in[0];
    const float* ptrans  = (const float*)d_in[1];
    const float* vt      = (const float*)d_in[2];
    const float* w       = (const float*)d_in[3];
    const float* tpose   = (const float*)d_in[4];
    const void*  parents = (const void*)d_in[5];
    const int*   kpv     = (const int*)d_in[6];
    const int*   kpj     = (const int*)d_in[7];
    const int*   kpb     = (const int*)d_in[8];

    float*  out = (float*)d_out;
    __bf16* Abf = (__bf16*)d_ws;                                 // 0.98 MB
    __bf16* Wbf = (__bf16*)((char*)d_ws + (size_t)MP12 * KP * 2); // 4.48 MB

    prep_kernel<<<B_ + PREPW_BLOCKS, 256, 0, stream>>>(
        rotvec, ptrans, tpose, parents, w, Abf, Wbf, out + OFF_J);

    dim3 grid(NSPLIT, MP12 / 192);  // (32, 16) = 512 blocks
    gemm_kernel<<<grid, 256, 0, stream>>>(Abf, Wbf, vt, out);

    kp_kernel<<<(B_ * NKP + 255) / 256, 256, 0, stream>>>(kpv, kpj, kpb, out);
}